// Round 2
// baseline (446.659 us; speedup 1.0000x reference)
//
#include <hip/hip_runtime.h>

typedef unsigned short u16;
typedef unsigned int u32;
typedef __attribute__((ext_vector_type(8))) short s8v;     // bf16 MFMA fragment (4 VGPR)
typedef __attribute__((ext_vector_type(4))) float f32x4;   // MFMA accumulator
typedef __attribute__((ext_vector_type(8))) u16 u16x8;
typedef __attribute__((ext_vector_type(4))) u16 u16x4;

#define DEV __device__ __forceinline__

DEV u16 f2bf(float x) {                    // RNE fp32 -> bf16 (bits)
  union { float f; u32 u; } v; v.f = x;
  u32 r = v.u + 0x7fffu + ((v.u >> 16) & 1u);
  return (u16)(r >> 16);
}
DEV float bf2f(u16 h) { union { u32 u; float f; } v; v.u = ((u32)h) << 16; return v.f; }
DEV void split2(float x, u16& h, u16& l) { h = f2bf(x); l = f2bf(x - bf2f(h)); }

DEV void gld16(const void* g, void* l) {
  __builtin_amdgcn_global_load_lds((const __attribute__((address_space(1))) void*)g,
                                   (__attribute__((address_space(3))) void*)l, 16, 0, 0);
}
DEV f32x4 mfma(s8v a, s8v b, f32x4 c) {
  return __builtin_amdgcn_mfma_f32_16x16x32_bf16(a, b, c, 0, 0, 0);
}

// ---------------- split fp32 -> bf16 hi/lo (8 elems/thread) ----------------
__global__ void __launch_bounds__(256) k_split(const float* __restrict__ in,
                                               u16* __restrict__ oh, u16* __restrict__ ol, int n8) {
  int i = blockIdx.x * 256 + threadIdx.x;
  if (i >= n8) return;
  const float4* p = (const float4*)in + (size_t)i * 2;
  float4 a = p[0], b = p[1];
  float v[8] = {a.x, a.y, a.z, a.w, b.x, b.y, b.z, b.w};
  u16x8 vh, vl;
#pragma unroll
  for (int j = 0; j < 8; ++j) { u16 h, l; split2(v[j], h, l); vh[j] = h; vl[j] = l; }
  ((u16x8*)oh)[i] = vh;
  ((u16x8*)ol)[i] = vl;
}

// ---------------- split-bf16 GEMM: C[m][n] = sum_k A[m][k]*B[n][k] ----------------
// A: x (8192x1024), B: weight (1024x1024), both hi/lo bf16; C fp32.
// 128x128 tile, BK=64, 4 waves (2x2 of 64x64), 16x16x32 MFMA, 3 split passes.
// bid&7 = n-tile = XCD (default round-robin) -> each XCD keeps its 512KB B-panel in L2.
__global__ void __launch_bounds__(256, 2) k_gemm(const u16* __restrict__ Ah, const u16* __restrict__ Al,
                                                 const u16* __restrict__ Bh, const u16* __restrict__ Bl,
                                                 float* __restrict__ C) {
  __shared__ u16 lds[32768];                 // 64KB: Ah,Al,Bh,Bl tiles [128][64], 8 16B-units/row, unit^=(row&7)
  u16* sAh = lds;
  u16* sAl = lds + 8192;
  u16* sBh = lds + 16384;
  u16* sBl = lds + 24576;
  const int tid = threadIdx.x;
  const int lane = tid & 63, w = tid >> 6;
  const int wm = w >> 1, wn = w & 1;
  const int l15 = lane & 15, g = lane >> 4;
  const int m0 = (int)(blockIdx.x >> 3) * 128;
  const int n0 = (int)(blockIdx.x & 7) * 128;

  f32x4 acc[4][4] = {};

  for (int kt = 0; kt < 16; ++kt) {
    const int k0 = kt * 64;
#pragma unroll
    for (int p = 0; p < 4; ++p) {
      int u = p * 256 + tid;
      int row = u >> 3, jp = u & 7;
      int j = jp ^ (row & 7);               // pre-swizzled global source, linear LDS dest
      size_t ga = (size_t)(m0 + row) * 1024 + k0 + j * 8;
      size_t gb = (size_t)(n0 + row) * 1024 + k0 + j * 8;
      gld16(Ah + ga, sAh + u * 8);
      gld16(Al + ga, sAl + u * 8);
      gld16(Bh + gb, sBh + u * 8);
      gld16(Bl + gb, sBl + u * 8);
    }
    __syncthreads();
#pragma unroll
    for (int ks = 0; ks < 2; ++ks) {
      s8v fah[4], fal[4], fbh[4], fbl[4];
#pragma unroll
      for (int mf = 0; mf < 4; ++mf) {
        int row = wm * 64 + mf * 16 + l15;
        int off = row * 64 + (((ks * 4 + g) ^ (row & 7)) * 8);
        fah[mf] = *(const s8v*)(sAh + off);
        fal[mf] = *(const s8v*)(sAl + off);
      }
#pragma unroll
      for (int nf = 0; nf < 4; ++nf) {
        int row = wn * 64 + nf * 16 + l15;
        int off = row * 64 + (((ks * 4 + g) ^ (row & 7)) * 8);
        fbh[nf] = *(const s8v*)(sBh + off);
        fbl[nf] = *(const s8v*)(sBl + off);
      }
#pragma unroll
      for (int mf = 0; mf < 4; ++mf)
#pragma unroll
        for (int nf = 0; nf < 4; ++nf) {    // split-bf16: hh + hl + lh passes
          acc[mf][nf] = mfma(fah[mf], fbh[nf], acc[mf][nf]);
          acc[mf][nf] = mfma(fah[mf], fbl[nf], acc[mf][nf]);
          acc[mf][nf] = mfma(fal[mf], fbh[nf], acc[mf][nf]);
        }
    }
    __syncthreads();
  }
#pragma unroll
  for (int mf = 0; mf < 4; ++mf)
#pragma unroll
    for (int nf = 0; nf < 4; ++nf)
#pragma unroll
      for (int r = 0; r < 4; ++r) {
        int m = m0 + wm * 64 + mf * 16 + g * 4 + r;   // C/D: col=lane&15, row=(lane>>4)*4+r
        int n = n0 + wn * 64 + nf * 16 + l15;
        C[(size_t)m * 1024 + n] = acc[mf][nf][r];
      }
}

// ---------------- RoPE (one tensor) + split -> [B,N,T,H] hi/lo ----------------
// scale folds 1/sqrt(H)*log2e into q (k passes scale=1).
__global__ void __launch_bounds__(256) k_rope(const float* __restrict__ zf,
                                              const float* __restrict__ cs, const float* __restrict__ sn,
                                              u16* __restrict__ zh, u16* __restrict__ zl, float scale) {
  const int bt = blockIdx.x;                 // b*2048 + t
  const int b = bt >> 11, t = bt & 2047;
  __shared__ float sz[1024];
  const int tid = threadIdx.x;
  ((float4*)sz)[tid] = ((const float4*)(zf + (size_t)bt * 1024))[tid];
  __syncthreads();
  const int i0 = tid * 4;
  float4 c4 = ((const float4*)(cs + (size_t)t * 1024))[tid];
  float4 s4 = ((const float4*)(sn + (size_t)t * 1024))[tid];
  float cc[4] = {c4.x, c4.y, c4.z, c4.w};
  float ss[4] = {s4.x, s4.y, s4.z, s4.w};
  u16x4 hv, lv;
#pragma unroll
  for (int j = 0; j < 4; ++j) {
    int i = i0 + j;
    float z;
    if (i < 512) z = sz[i] * cc[j] - sz[2 * i + 1] * ss[j];        // rot[i] = -z[2i+1]
    else         z = sz[i] * cc[j] + sz[2 * (i - 512)] * ss[j];    // rot[512+i'] = z[2i']
    z *= scale;
    u16 h, l;
    split2(z, h, l); hv[j] = h; lv[j] = l;
  }
  const int n = i0 >> 7, hh = i0 & 127;
  const size_t o = ((size_t)(b * 8 + n) * 2048 + t) * 128 + hh;
  *(u16x4*)(zh + o) = hv;
  *(u16x4*)(zl + o) = lv;
}

// ---------------- V transpose + split: [B,T,N*H] fp32 -> [B,N,H,T] bf16 hi/lo ----------------
__global__ void __launch_bounds__(256) k_vtrans(const float* __restrict__ vf,
                                                u16* __restrict__ vth, u16* __restrict__ vtl) {
  const int bid = blockIdx.x;                // (b*8+n)*32 + tt
  const int tt = bid & 31, bn = bid >> 5;
  const int b = bn >> 3, n = bn & 7;
  const int t0 = tt * 64;
  __shared__ float s[64][129];
  const int tid = threadIdx.x;
#pragma unroll
  for (int r8 = 0; r8 < 8; ++r8) {
    int row = r8 * 8 + (tid >> 5);
    int c4 = tid & 31;
    float4 v = *(const float4*)(vf + ((size_t)b * 2048 + t0 + row) * 1024 + n * 128 + c4 * 4);
    s[row][c4 * 4 + 0] = v.x; s[row][c4 * 4 + 1] = v.y;
    s[row][c4 * 4 + 2] = v.z; s[row][c4 * 4 + 3] = v.w;
  }
  __syncthreads();
  const int h = tid >> 1, half = tid & 1;
  const size_t ob = ((size_t)bn * 128 + h) * 2048 + t0 + half * 32;
  u16x8 vh[4], vl[4];
#pragma unroll
  for (int j = 0; j < 32; ++j) {
    u16 a, c;
    split2(s[half * 32 + j][h], a, c);
    vh[j >> 3][j & 7] = a;
    vl[j >> 3][j & 7] = c;
  }
#pragma unroll
  for (int j = 0; j < 4; ++j) {
    *(u16x8*)(vth + ob + j * 8) = vh[j];
    *(u16x8*)(vtl + ob + j * 8) = vl[j];
  }
}

// ---------------- flash attention, split-bf16, swapped operands ----------------
// Block: 4 waves x 32 q-rows = 128 q. KVBLK=64. St[kk][q] = mfma(K, Q); Ot[h][q] = mfma(Vt, P).
// qt remap: bid and bid+256 land on the same CU (XCD round-robin) -> pair work sums to 34 steps.
__global__ void __launch_bounds__(256, 2) k_attn(const u16* __restrict__ Qh, const u16* __restrict__ Ql,
                                                 const u16* __restrict__ Kh, const u16* __restrict__ Kl,
                                                 const u16* __restrict__ Vh, const u16* __restrict__ Vl,
                                                 float* __restrict__ Out) {
  const int bid = blockIdx.x;
  const int bn = bid & 31;                   // b*8+n
  const int ord = bid >> 5;                  // [0,16)
  const int qt = (ord < 8) ? (15 - ord) : (ord - 8);
  const int b = bn >> 3, n = bn & 7;
  const int q0 = qt * 128;
  const int tid = threadIdx.x;
  const int lane = tid & 63, w = tid >> 6;
  const int l15 = lane & 15, g = lane >> 4;

  __shared__ u16 sm[32768];                  // 64KB
  u16* sKh = sm;                             // [64][128] bf16, 16 16B-units/row, unit^=(row&15)
  u16* sKl = sm + 8192;
  u16* sVh = sm + 16384;                     // [128][64] bf16, 8 units/row, unit^=(row&7)
  u16* sVl = sm + 24576;
  u16* sPh = sKh + w * 2048;                 // P aliases K region after barrier: per-wave [32 q][64 kk]
  u16* sPl = sKl + w * 2048;

  // Q fragments (held in registers for the whole block)
  s8v fqh[2][4], fql[2][4];
#pragma unroll
  for (int jf = 0; jf < 2; ++jf) {
    const size_t qoff = ((size_t)bn * 2048 + (q0 + w * 32 + jf * 16 + l15)) * 128 + g * 8;
#pragma unroll
    for (int hs = 0; hs < 4; ++hs) {
      fqh[jf][hs] = *(const s8v*)(Qh + qoff + hs * 32);
      fql[jf][hs] = *(const s8v*)(Ql + qoff + hs * 32);
    }
  }

  f32x4 ot[8][2] = {};                       // Ot[h=hf*16+g*4+r][q=jf*16+l15]
  float mrun[2] = {-1e30f, -1e30f};
  float lrun[2] = {0.f, 0.f};

  const size_t kbase = (size_t)bn * 2048 * 128;   // same flat base for K ([t][h]) and Vt ([h][t])
  const int nkv = 2 * qt + 2;

  for (int kv = 0; kv < nkv; ++kv) {
    const int k0 = kv * 64;
    // ---- stage K and Vt tiles (hi+lo), pre-swizzled global source, linear LDS dest
#pragma unroll
    for (int p = 0; p < 4; ++p) {
      int u = p * 256 + tid;
      { int row = u >> 4, jp = u & 15, j = jp ^ (row & 15);
        size_t go = kbase + (size_t)(k0 + row) * 128 + j * 8;
        gld16(Kh + go, sKh + u * 8);
        gld16(Kl + go, sKl + u * 8); }
      { int row = u >> 3, jp = u & 7, j = jp ^ (row & 7);
        size_t go = kbase + (size_t)row * 2048 + k0 + j * 8;
        gld16(Vh + go, sVh + u * 8);
        gld16(Vl + go, sVl + u * 8); }
    }
    __syncthreads();

    // ---- QK^T (swapped): St[kk][q], 3 split passes
    f32x4 st[4][2] = {};
#pragma unroll
    for (int f = 0; f < 4; ++f) {
      const int row = f * 16 + l15;
      const u16* bh = sKh + row * 128;
      const u16* bl = sKl + row * 128;
#pragma unroll
      for (int hs = 0; hs < 4; ++hs) {
        const int j = (((hs * 4 + g) ^ (row & 15)) * 8);
        s8v akh = *(const s8v*)(bh + j);
        s8v akl = *(const s8v*)(bl + j);
#pragma unroll
        for (int jf = 0; jf < 2; ++jf) {
          st[f][jf] = mfma(akh, fqh[jf][hs], st[f][jf]);
          st[f][jf] = mfma(akh, fql[jf][hs], st[f][jf]);
          st[f][jf] = mfma(akl, fqh[jf][hs], st[f][jf]);
        }
      }
    }
    __syncthreads();   // all QK reads of sK done before P overwrites that region

    // ---- mask + online softmax (log2 domain) + P split written to LDS
#pragma unroll
    for (int jf = 0; jf < 2; ++jf) {
      const int qg = q0 + w * 32 + jf * 16 + l15;
      if (k0 + 63 > q0 + w * 32 + jf * 16) {
#pragma unroll
        for (int f = 0; f < 4; ++f)
#pragma unroll
          for (int r = 0; r < 4; ++r)
            if (k0 + f * 16 + g * 4 + r > qg) st[f][jf][r] = -1e30f;
      }
      float tm = -1e30f;
#pragma unroll
      for (int f = 0; f < 4; ++f)
#pragma unroll
        for (int r = 0; r < 4; ++r) tm = fmaxf(tm, st[f][jf][r]);
      tm = fmaxf(tm, __shfl_xor(tm, 16));
      tm = fmaxf(tm, __shfl_xor(tm, 32));
      const float mnew = fmaxf(mrun[jf], tm);
      const float corr = exp2f(mrun[jf] - mnew);
      mrun[jf] = mnew;
      float ps = 0.f;
      const int q = jf * 16 + l15;
#pragma unroll
      for (int f = 0; f < 4; ++f) {
        u16x4 p4h, p4l;
#pragma unroll
        for (int r = 0; r < 4; ++r) {
          float p = exp2f(st[f][jf][r] - mnew);
          ps += p;
          u16 hh, ll;
          split2(p, hh, ll);
          p4h[r] = hh; p4l[r] = ll;
        }
        const int off = q * 64 + (((2 * f + (g >> 1)) ^ (q & 7)) * 8) + (g & 1) * 4;
        *(u16x4*)(sPh + off) = p4h;
        *(u16x4*)(sPl + off) = p4l;
      }
      ps += __shfl_xor(ps, 16);
      ps += __shfl_xor(ps, 32);
      lrun[jf] = lrun[jf] * corr + ps;
#pragma unroll
      for (int hf = 0; hf < 8; ++hf) {
        ot[hf][jf][0] *= corr; ot[hf][jf][1] *= corr;
        ot[hf][jf][2] *= corr; ot[hf][jf][3] *= corr;
      }
    }
    asm volatile("" ::: "memory");   // keep P ds_writes ordered before PV ds_reads (wave-private, HW in-order)

    // ---- PV: Ot[h][q] += Vt * P (wave-private P, no barrier needed)
    s8v fph[2][2], fpl[2][2];
#pragma unroll
    for (int jf = 0; jf < 2; ++jf) {
      const int q = jf * 16 + l15;
#pragma unroll
      for (int c = 0; c < 2; ++c) {
        const int off = q * 64 + (((4 * c + g) ^ (q & 7)) * 8);
        fph[jf][c] = *(const s8v*)(sPh + off);
        fpl[jf][c] = *(const s8v*)(sPl + off);
      }
    }
#pragma unroll
    for (int hf = 0; hf < 8; ++hf) {
      const int row = hf * 16 + l15;
      const int sw = row & 7;
#pragma unroll
      for (int c = 0; c < 2; ++c) {
        const int off = row * 64 + (((4 * c + g) ^ sw) * 8);
        s8v avh = *(const s8v*)(sVh + off);
        s8v avl = *(const s8v*)(sVl + off);
#pragma unroll
        for (int jf = 0; jf < 2; ++jf) {
          ot[hf][jf] = mfma(avh, fph[jf][c], ot[hf][jf]);
          ot[hf][jf] = mfma(avl, fph[jf][c], ot[hf][jf]);
          ot[hf][jf] = mfma(avh, fpl[jf][c], ot[hf][jf]);
        }
      }
    }
    __syncthreads();   // before next tile's staging overwrites sK/sV
  }

  // ---- epilogue: normalize, write out[b, t, n*128+h] as float4 (64B segments)
#pragma unroll
  for (int jf = 0; jf < 2; ++jf) {
    const float inv = 1.0f / lrun[jf];
    const int qrow = q0 + w * 32 + jf * 16 + l15;
    const size_t ob = ((size_t)b * 2048 + qrow) * 1024 + n * 128;
#pragma unroll
    for (int hf = 0; hf < 8; ++hf) {
      float4 o4;
      o4.x = ot[hf][jf][0] * inv; o4.y = ot[hf][jf][1] * inv;
      o4.z = ot[hf][jf][2] * inv; o4.w = ot[hf][jf][3] * inv;
      *(float4*)(Out + ob + hf * 16 + g * 4) = o4;
    }
  }
}

// ---------------- host ----------------
extern "C" void kernel_launch(void* const* d_in, const int* in_sizes, int n_in,
                              void* d_out, int out_size, void* d_ws, size_t ws_size,
                              hipStream_t stream) {
  const float* x  = (const float*)d_in[0];
  const float* wq = (const float*)d_in[1];
  const float* wk = (const float*)d_in[2];
  const float* wv = (const float*)d_in[3];
  const float* cs = (const float*)d_in[4];
  const float* sn = (const float*)d_in[5];
  float* out = (float*)d_out;

  // Workspace plan (peak 146,800,640 B) with lifetime-chained aliasing:
  //   [pool A: 23,068,672 u16] xh,xl + 6 weight splits   (dead after GEMMs)
  //   [qf][kf][vf] fp32 8,388,608 each                   (dead after their rope/vtrans)
  //   qh/ql  alias pool A   (written by rope_q after GEMMs)
  //   kh/kl  alias qf       (written by rope_k after rope_q)
  //   vth/vtl alias kf      (written by vtrans after rope_k)
  u16* xh  = (u16*)d_ws;
  u16* xl  = xh + 8388608;
  u16* wqh = xl + 8388608;
  u16* wql = wqh + 1048576;
  u16* wkh = wql + 1048576;
  u16* wkl = wkh + 1048576;
  u16* wvh = wkl + 1048576;
  u16* wvl = wvh + 1048576;
  float* qf = (float*)(wvl + 1048576);
  float* kf = qf + 8388608;
  float* vf = kf + 8388608;
  u16* qh = xh;               // aliases (see plan)
  u16* ql = xl;
  u16* kh = (u16*)qf;
  u16* kl = kh + 8388608;
  u16* vth = (u16*)kf;
  u16* vtl = vth + 8388608;

  if (ws_size < (size_t)146800640) return;  // insufficient scratch -> clean validation failure

  const float QS = 0.08838834764831845f * 1.4426950408889634f;  // 1/sqrt(128) * log2(e)

  k_split<<<4096, 256, 0, stream>>>(x, xh, xl, 1048576);
  k_split<<<512, 256, 0, stream>>>(wq, wqh, wql, 131072);
  k_split<<<512, 256, 0, stream>>>(wk, wkh, wkl, 131072);
  k_split<<<512, 256, 0, stream>>>(wv, wvh, wvl, 131072);
  k_gemm<<<512, 256, 0, stream>>>(xh, xl, wqh, wql, qf);
  k_gemm<<<512, 256, 0, stream>>>(xh, xl, wkh, wkl, kf);
  k_gemm<<<512, 256, 0, stream>>>(xh, xl, wvh, wvl, vf);
  k_rope<<<8192, 256, 0, stream>>>(qf, cs, sn, qh, ql, QS);   // q: fold scale*log2e
  k_rope<<<8192, 256, 0, stream>>>(kf, cs, sn, kh, kl, 1.0f); // k: no scale
  k_vtrans<<<1024, 256, 0, stream>>>(vf, vth, vtl);
  k_attn<<<512, 256, 0, stream>>>(qh, ql, kh, kl, vth, vtl, out);
}

// Round 3
// 406.259 us; speedup vs baseline: 1.0994x; 1.0994x over previous
//
#include <hip/hip_runtime.h>

typedef unsigned short u16;
typedef unsigned int u32;
typedef __attribute__((ext_vector_type(8))) short s8v;     // bf16 MFMA fragment (4 VGPR)
typedef __attribute__((ext_vector_type(4))) float f32x4;   // MFMA accumulator
typedef __attribute__((ext_vector_type(8))) u16 u16x8;
typedef __attribute__((ext_vector_type(4))) u16 u16x4;

#define DEV __device__ __forceinline__

DEV u16 f2bf(float x) {                    // RNE fp32 -> bf16 (bits)
  union { float f; u32 u; } v; v.f = x;
  u32 r = v.u + 0x7fffu + ((v.u >> 16) & 1u);
  return (u16)(r >> 16);
}
DEV float bf2f(u16 h) { union { u32 u; float f; } v; v.u = ((u32)h) << 16; return v.f; }
DEV void split2(float x, u16& h, u16& l) { h = f2bf(x); l = f2bf(x - bf2f(h)); }

DEV void gld16(const void* g, void* l) {
  __builtin_amdgcn_global_load_lds((const __attribute__((address_space(1))) void*)g,
                                   (__attribute__((address_space(3))) void*)l, 16, 0, 0);
}
DEV f32x4 mfma(s8v a, s8v b, f32x4 c) {
  return __builtin_amdgcn_mfma_f32_16x16x32_bf16(a, b, c, 0, 0, 0);
}

// ---------------- split fp32 -> bf16 hi/lo (8 elems/thread) ----------------
__global__ void __launch_bounds__(256) k_split(const float* __restrict__ in,
                                               u16* __restrict__ oh, u16* __restrict__ ol, int n8) {
  int i = blockIdx.x * 256 + threadIdx.x;
  if (i >= n8) return;
  const float4* p = (const float4*)in + (size_t)i * 2;
  float4 a = p[0], b = p[1];
  float v[8] = {a.x, a.y, a.z, a.w, b.x, b.y, b.z, b.w};
  u16x8 vh, vl;
#pragma unroll
  for (int j = 0; j < 8; ++j) { u16 h, l; split2(v[j], h, l); vh[j] = h; vl[j] = l; }
  ((u16x8*)oh)[i] = vh;
  ((u16x8*)ol)[i] = vl;
}

// ---------------- fused QKV split-bf16 GEMM ----------------
// C[m][n] = sum_k A[m][k]*B[n][k]; A = x (8192x1024), B = one of wq/wk/wv (1024x1024).
// 128x128 tile, BK=64, 4 waves (2x2 of 64x64), 16x16x32 MFMA, 3 split passes (hh+hl+lh).
// bid = nt*64 + mt: consecutive bids share the B-panel across XCDs (each XCD's L2 keeps it).
__global__ void __launch_bounds__(256, 2) k_gemm_qkv(
    const u16* __restrict__ Ah, const u16* __restrict__ Al,
    const u16* __restrict__ wqh, const u16* __restrict__ wql,
    const u16* __restrict__ wkh, const u16* __restrict__ wkl,
    const u16* __restrict__ wvh, const u16* __restrict__ wvl,
    float* __restrict__ qf, float* __restrict__ kf, float* __restrict__ vf) {
  __shared__ u16 lds[32768];                 // 64KB: A-hi, A-lo, B-hi, B-lo tiles [128][64]
  u16* sAh = lds;
  u16* sAl = lds + 8192;
  u16* sBh = lds + 16384;
  u16* sBl = lds + 24576;
  const int tid = threadIdx.x;
  const int lane = tid & 63, w = tid >> 6;
  const int wm = w >> 1, wn = w & 1;
  const int l15 = lane & 15, g = lane >> 4;
  const int bid = blockIdx.x;
  const int mt = bid & 63, nt = bid >> 6;    // nt 0..23
  const u16* Bh; const u16* Bl; float* C;
  if (nt < 8)       { Bh = wqh; Bl = wql; C = qf; }
  else if (nt < 16) { Bh = wkh; Bl = wkl; C = kf; }
  else              { Bh = wvh; Bl = wvl; C = vf; }
  const int m0 = mt * 128;
  const int n0 = (nt & 7) * 128;

  f32x4 acc[4][4] = {};

  for (int kt = 0; kt < 16; ++kt) {
    const int k0 = kt * 64;
#pragma unroll
    for (int p = 0; p < 4; ++p) {
      int u = p * 256 + tid;
      int row = u >> 3, jp = u & 7;
      int j = jp ^ (row & 7);               // pre-swizzled global source, linear LDS dest
      size_t ga = (size_t)(m0 + row) * 1024 + k0 + j * 8;
      size_t gb = (size_t)(n0 + row) * 1024 + k0 + j * 8;
      gld16(Ah + ga, sAh + u * 8);
      gld16(Al + ga, sAl + u * 8);
      gld16(Bh + gb, sBh + u * 8);
      gld16(Bl + gb, sBl + u * 8);
    }
    __syncthreads();
#pragma unroll
    for (int ks = 0; ks < 2; ++ks) {
      s8v fah[4], fal[4], fbh[4], fbl[4];
#pragma unroll
      for (int mf = 0; mf < 4; ++mf) {
        int row = wm * 64 + mf * 16 + l15;
        int off = row * 64 + (((ks * 4 + g) ^ (row & 7)) * 8);
        fah[mf] = *(const s8v*)(sAh + off);
        fal[mf] = *(const s8v*)(sAl + off);
      }
#pragma unroll
      for (int nf = 0; nf < 4; ++nf) {
        int row = wn * 64 + nf * 16 + l15;
        int off = row * 64 + (((ks * 4 + g) ^ (row & 7)) * 8);
        fbh[nf] = *(const s8v*)(sBh + off);
        fbl[nf] = *(const s8v*)(sBl + off);
      }
#pragma unroll
      for (int mf = 0; mf < 4; ++mf)
#pragma unroll
        for (int nf = 0; nf < 4; ++nf) {    // split-bf16: hh + hl + lh
          acc[mf][nf] = mfma(fah[mf], fbh[nf], acc[mf][nf]);
          acc[mf][nf] = mfma(fah[mf], fbl[nf], acc[mf][nf]);
          acc[mf][nf] = mfma(fal[mf], fbh[nf], acc[mf][nf]);
        }
    }
    __syncthreads();
  }
#pragma unroll
  for (int mf = 0; mf < 4; ++mf)
#pragma unroll
    for (int nf = 0; nf < 4; ++nf)
#pragma unroll
      for (int r = 0; r < 4; ++r) {
        int m = m0 + wm * 64 + mf * 16 + g * 4 + r;   // C/D: col=lane&15, row=(lane>>4)*4+r
        int n = n0 + wn * 64 + nf * 16 + l15;
        C[(size_t)m * 1024 + n] = acc[mf][nf][r];
      }
}

// ---------------- RoPE (one tensor) + split -> [B,N,T,H] hi/lo ----------------
__global__ void __launch_bounds__(256) k_rope(const float* __restrict__ zf,
                                              const float* __restrict__ cs, const float* __restrict__ sn,
                                              u16* __restrict__ zh, u16* __restrict__ zl, float scale) {
  const int bt = blockIdx.x;                 // b*2048 + t
  const int b = bt >> 11, t = bt & 2047;
  __shared__ float sz[1024];
  const int tid = threadIdx.x;
  ((float4*)sz)[tid] = ((const float4*)(zf + (size_t)bt * 1024))[tid];
  __syncthreads();
  const int i0 = tid * 4;
  float4 c4 = ((const float4*)(cs + (size_t)t * 1024))[tid];
  float4 s4 = ((const float4*)(sn + (size_t)t * 1024))[tid];
  float cc[4] = {c4.x, c4.y, c4.z, c4.w};
  float ss[4] = {s4.x, s4.y, s4.z, s4.w};
  u16x4 hv, lv;
#pragma unroll
  for (int j = 0; j < 4; ++j) {
    int i = i0 + j;
    float z;
    if (i < 512) z = sz[i] * cc[j] - sz[2 * i + 1] * ss[j];        // rot[i] = -z[2i+1]
    else         z = sz[i] * cc[j] + sz[2 * (i - 512)] * ss[j];    // rot[512+i'] = z[2i']
    z *= scale;
    u16 h, l;
    split2(z, h, l); hv[j] = h; lv[j] = l;
  }
  const int n = i0 >> 7, hh = i0 & 127;
  const size_t o = ((size_t)(b * 8 + n) * 2048 + t) * 128 + hh;
  *(u16x4*)(zh + o) = hv;
  *(u16x4*)(zl + o) = lv;
}

// ---------------- V transpose + split: [B,T,N*H] fp32 -> [B,N,H,T] bf16 hi/lo ----------------
__global__ void __launch_bounds__(256) k_vtrans(const float* __restrict__ vf,
                                                u16* __restrict__ vth, u16* __restrict__ vtl) {
  const int bid = blockIdx.x;                // (b*8+n)*32 + tt
  const int tt = bid & 31, bn = bid >> 5;
  const int b = bn >> 3, n = bn & 7;
  const int t0 = tt * 64;
  __shared__ float s[64][129];
  const int tid = threadIdx.x;
#pragma unroll
  for (int r8 = 0; r8 < 8; ++r8) {
    int row = r8 * 8 + (tid >> 5);
    int c4 = tid & 31;
    float4 v = *(const float4*)(vf + ((size_t)b * 2048 + t0 + row) * 1024 + n * 128 + c4 * 4);
    s[row][c4 * 4 + 0] = v.x; s[row][c4 * 4 + 1] = v.y;
    s[row][c4 * 4 + 2] = v.z; s[row][c4 * 4 + 3] = v.w;
  }
  __syncthreads();
  const int h = tid >> 1, half = tid & 1;
  const size_t ob = ((size_t)bn * 128 + h) * 2048 + t0 + half * 32;
  u16x8 vh[4], vl[4];
#pragma unroll
  for (int j = 0; j < 32; ++j) {
    u16 a, c;
    split2(s[half * 32 + j][h], a, c);
    vh[j >> 3][j & 7] = a;
    vl[j >> 3][j & 7] = c;
  }
#pragma unroll
  for (int j = 0; j < 4; ++j) {
    *(u16x8*)(vth + ob + j * 8) = vh[j];
    *(u16x8*)(vtl + ob + j * 8) = vl[j];
  }
}

// ---------------- flash attention, split-bf16, swapped operands, QBLK=64 ----------------
// Block: 4 waves, each wave owns 16 q-rows. KVBLK=64. 1024 jobs (32 bn x 32 qt), launched
// big-jobs-first: blocks 0..511 (qt 31..16) fill all 512 CU slots; short jobs backfill (LPT).
// St[kk][q] = mfma(K, Q); Ot[h][q] = mfma(Vt, P).
__global__ void __launch_bounds__(256, 2) k_attn(const u16* __restrict__ Qh, const u16* __restrict__ Ql,
                                                 const u16* __restrict__ Kh, const u16* __restrict__ Kl,
                                                 const u16* __restrict__ Vh, const u16* __restrict__ Vl,
                                                 float* __restrict__ Out) {
  const int bid = blockIdx.x;
  const int bn = bid & 31;                   // b*8+n
  const int qt = 31 - (bid >> 5);            // 0..31, descending job size in launch order
  const int b = bn >> 3, n = bn & 7;
  const int q0 = qt * 64;
  const int tid = threadIdx.x;
  const int lane = tid & 63, w = tid >> 6;
  const int l15 = lane & 15, g = lane >> 4;

  __shared__ u16 sm[32768];                  // 64KB
  u16* sKh = sm;                             // [64][128] bf16, 16 16B-units/row, unit^=(row&15)
  u16* sKl = sm + 8192;
  u16* sVh = sm + 16384;                     // [128][64] bf16, 8 units/row, unit^=(row&7)
  u16* sVl = sm + 24576;
  u16* sPh = sKh + w * 1024;                 // P aliases K region after barrier: per-wave [16 q][64 kk]
  u16* sPl = sKl + w * 1024;

  // Q fragments (held in registers for the whole block); q-row = q0 + w*16 + l15
  s8v fqh[4], fql[4];
  {
    const size_t qoff = ((size_t)bn * 2048 + (q0 + w * 16 + l15)) * 128 + g * 8;
#pragma unroll
    for (int hs = 0; hs < 4; ++hs) {
      fqh[hs] = *(const s8v*)(Qh + qoff + hs * 32);
      fql[hs] = *(const s8v*)(Ql + qoff + hs * 32);
    }
  }

  f32x4 ot[8] = {};                          // Ot[h=hf*16+g*4+r][q=l15]
  float mrun = -1e30f;
  float lrun = 0.f;

  const size_t kbase = (size_t)bn * 2048 * 128;   // same flat base for K ([t][h]) and Vt ([h][t])
  const int nkv = qt + 1;

  for (int kv = 0; kv < nkv; ++kv) {
    const int k0 = kv * 64;
    // ---- stage K and Vt tiles (hi+lo), pre-swizzled global source, linear LDS dest
#pragma unroll
    for (int p = 0; p < 4; ++p) {
      int u = p * 256 + tid;
      { int row = u >> 4, jp = u & 15, j = jp ^ (row & 15);
        size_t go = kbase + (size_t)(k0 + row) * 128 + j * 8;
        gld16(Kh + go, sKh + u * 8);
        gld16(Kl + go, sKl + u * 8); }
      { int row = u >> 3, jp = u & 7, j = jp ^ (row & 7);
        size_t go = kbase + (size_t)row * 2048 + k0 + j * 8;
        gld16(Vh + go, sVh + u * 8);
        gld16(Vl + go, sVl + u * 8); }
    }
    __syncthreads();

    // ---- QK^T (swapped): St[kk][q], 3 split passes
    f32x4 st[4] = {};
#pragma unroll
    for (int f = 0; f < 4; ++f) {
      const int row = f * 16 + l15;
      const u16* bh = sKh + row * 128;
      const u16* bl = sKl + row * 128;
#pragma unroll
      for (int hs = 0; hs < 4; ++hs) {
        const int j = (((hs * 4 + g) ^ (row & 15)) * 8);
        s8v akh = *(const s8v*)(bh + j);
        s8v akl = *(const s8v*)(bl + j);
        st[f] = mfma(akh, fqh[hs], st[f]);
        st[f] = mfma(akh, fql[hs], st[f]);
        st[f] = mfma(akl, fqh[hs], st[f]);
      }
    }
    __syncthreads();   // all QK reads of sK done before P overwrites that region

    // ---- mask + online softmax (log2 domain) + P split written to LDS
    {
      const int qg = q0 + w * 16 + l15;
      if (k0 + 63 > q0 + w * 16) {
#pragma unroll
        for (int f = 0; f < 4; ++f)
#pragma unroll
          for (int r = 0; r < 4; ++r)
            if (k0 + f * 16 + g * 4 + r > qg) st[f][r] = -1e30f;
      }
      float tm = -1e30f;
#pragma unroll
      for (int f = 0; f < 4; ++f)
#pragma unroll
        for (int r = 0; r < 4; ++r) tm = fmaxf(tm, st[f][r]);
      tm = fmaxf(tm, __shfl_xor(tm, 16));
      tm = fmaxf(tm, __shfl_xor(tm, 32));
      const float mnew = fmaxf(mrun, tm);
      const float corr = exp2f(mrun - mnew);
      mrun = mnew;
      float ps = 0.f;
      const int q = l15;
#pragma unroll
      for (int f = 0; f < 4; ++f) {
        u16x4 p4h, p4l;
#pragma unroll
        for (int r = 0; r < 4; ++r) {
          float p = exp2f(st[f][r] - mnew);
          ps += p;
          u16 hh, ll;
          split2(p, hh, ll);
          p4h[r] = hh; p4l[r] = ll;
        }
        const int off = q * 64 + (((2 * f + (g >> 1)) ^ (q & 7)) * 8) + (g & 1) * 4;
        *(u16x4*)(sPh + off) = p4h;
        *(u16x4*)(sPl + off) = p4l;
      }
      ps += __shfl_xor(ps, 16);
      ps += __shfl_xor(ps, 32);
      lrun = lrun * corr + ps;
#pragma unroll
      for (int hf = 0; hf < 8; ++hf) {
        ot[hf][0] *= corr; ot[hf][1] *= corr;
        ot[hf][2] *= corr; ot[hf][3] *= corr;
      }
    }
    asm volatile("" ::: "memory");   // keep P ds_writes ordered before PV ds_reads (wave-private, HW in-order)

    // ---- PV: Ot[h][q] += Vt * P (wave-private P, no barrier needed)
    s8v fph[2], fpl[2];
    {
      const int q = l15;
#pragma unroll
      for (int c = 0; c < 2; ++c) {
        const int off = q * 64 + (((4 * c + g) ^ (q & 7)) * 8);
        fph[c] = *(const s8v*)(sPh + off);
        fpl[c] = *(const s8v*)(sPl + off);
      }
    }
#pragma unroll
    for (int hf = 0; hf < 8; ++hf) {
      const int row = hf * 16 + l15;
      const int sw = row & 7;
#pragma unroll
      for (int c = 0; c < 2; ++c) {
        const int off = row * 64 + (((4 * c + g) ^ sw) * 8);
        s8v avh = *(const s8v*)(sVh + off);
        s8v avl = *(const s8v*)(sVl + off);
        ot[hf] = mfma(avh, fph[c], ot[hf]);
        ot[hf] = mfma(avl, fph[c], ot[hf]);
        ot[hf] = mfma(avh, fpl[c], ot[hf]);
      }
    }
    __syncthreads();   // before next tile's staging overwrites sK/sV
  }

  // ---- epilogue: normalize, write out[b, t, n*128+h] as float4 (64B segments)
  {
    const float inv = 1.0f / lrun;
    const int qrow = q0 + w * 16 + l15;
    const size_t ob = ((size_t)b * 2048 + qrow) * 1024 + n * 128;
#pragma unroll
    for (int hf = 0; hf < 8; ++hf) {
      float4 o4;
      o4.x = ot[hf][0] * inv; o4.y = ot[hf][1] * inv;
      o4.z = ot[hf][2] * inv; o4.w = ot[hf][3] * inv;
      *(float4*)(Out + ob + hf * 16 + g * 4) = o4;
    }
  }
}

// ---------------- host ----------------
extern "C" void kernel_launch(void* const* d_in, const int* in_sizes, int n_in,
                              void* d_out, int out_size, void* d_ws, size_t ws_size,
                              hipStream_t stream) {
  const float* x  = (const float*)d_in[0];
  const float* wq = (const float*)d_in[1];
  const float* wk = (const float*)d_in[2];
  const float* wv = (const float*)d_in[3];
  const float* cs = (const float*)d_in[4];
  const float* sn = (const float*)d_in[5];
  float* out = (float*)d_out;

  // Workspace plan (peak 146,800,640 B) with lifetime-chained aliasing:
  //   [pool A: 23,068,672 u16] xh,xl + 6 weight splits   (dead after GEMMs)
  //   [qf][kf][vf] fp32 8,388,608 each                   (dead after their rope/vtrans)
  //   qh/ql  alias pool A; kh/kl alias qf; vth/vtl alias kf
  u16* xh  = (u16*)d_ws;
  u16* xl  = xh + 8388608;
  u16* wqh = xl + 8388608;
  u16* wql = wqh + 1048576;
  u16* wkh = wql + 1048576;
  u16* wkl = wkh + 1048576;
  u16* wvh = wkl + 1048576;
  u16* wvl = wvh + 1048576;
  float* qf = (float*)(wvl + 1048576);
  float* kf = qf + 8388608;
  float* vf = kf + 8388608;
  u16* qh = xh;               // aliases (see plan)
  u16* ql = xl;
  u16* kh = (u16*)qf;
  u16* kl = kh + 8388608;
  u16* vth = (u16*)kf;
  u16* vtl = vth + 8388608;

  if (ws_size < (size_t)146800640) return;  // insufficient scratch -> clean validation failure

  const float QS = 0.08838834764831845f * 1.4426950408889634f;  // 1/sqrt(128) * log2(e)

  k_split<<<4096, 256, 0, stream>>>(x, xh, xl, 1048576);
  k_split<<<512, 256, 0, stream>>>(wq, wqh, wql, 131072);
  k_split<<<512, 256, 0, stream>>>(wk, wkh, wkl, 131072);
  k_split<<<512, 256, 0, stream>>>(wv, wvh, wvl, 131072);
  k_gemm_qkv<<<1536, 256, 0, stream>>>(xh, xl, wqh, wql, wkh, wkl, wvh, wvl, qf, kf, vf);
  k_rope<<<8192, 256, 0, stream>>>(qf, cs, sn, qh, ql, QS);   // q: fold scale*log2e
  k_rope<<<8192, 256, 0, stream>>>(kf, cs, sn, kh, kl, 1.0f); // k: no scale
  k_vtrans<<<1024, 256, 0, stream>>>(vf, vth, vtl);
  k_attn<<<1024, 256, 0, stream>>>(qh, ql, kh, kl, vth, vtl, out);
}

// Round 4
// 366.564 us; speedup vs baseline: 1.2185x; 1.1083x over previous
//
#include <hip/hip_runtime.h>

typedef unsigned short u16;
typedef unsigned int u32;
typedef __attribute__((ext_vector_type(8))) short s8v;        // bf16 MFMA fragment (4 VGPR)
typedef __attribute__((ext_vector_type(8))) _Float16 h8v;     // fp16 MFMA fragment (4 VGPR)
typedef __attribute__((ext_vector_type(4))) float f32x4;      // MFMA accumulator
typedef __attribute__((ext_vector_type(8))) u16 u16x8;
typedef __attribute__((ext_vector_type(4))) u16 u16x4;

#define DEV __device__ __forceinline__

DEV u16 f2bf(float x) {                    // RNE fp32 -> bf16 (bits)
  union { float f; u32 u; } v; v.f = x;
  u32 r = v.u + 0x7fffu + ((v.u >> 16) & 1u);
  return (u16)(r >> 16);
}
DEV float bf2f(u16 h) { union { u32 u; float f; } v; v.u = ((u32)h) << 16; return v.f; }
DEV void split2(float x, u16& h, u16& l) { h = f2bf(x); l = f2bf(x - bf2f(h)); }

DEV void gld16(const void* g, void* l) {
  __builtin_amdgcn_global_load_lds((const __attribute__((address_space(1))) void*)g,
                                   (__attribute__((address_space(3))) void*)l, 16, 0, 0);
}
DEV f32x4 mfma(s8v a, s8v b, f32x4 c) {
  return __builtin_amdgcn_mfma_f32_16x16x32_bf16(a, b, c, 0, 0, 0);
}
DEV f32x4 mfma16(h8v a, h8v b, f32x4 c) {
  return __builtin_amdgcn_mfma_f32_16x16x32_f16(a, b, c, 0, 0, 0);
}

// ---------------- convert fp32 -> fp16 (8 elems/thread) ----------------
__global__ void __launch_bounds__(256) k_split_h(const float* __restrict__ in,
                                                 _Float16* __restrict__ oh, int n8) {
  int i = blockIdx.x * 256 + threadIdx.x;
  if (i >= n8) return;
  const float4* p = (const float4*)in + (size_t)i * 2;
  float4 a = p[0], b = p[1];
  float v[8] = {a.x, a.y, a.z, a.w, b.x, b.y, b.z, b.w};
  h8v o;
#pragma unroll
  for (int j = 0; j < 8; ++j) o[j] = (_Float16)v[j];
  ((h8v*)oh)[i] = o;
}

// ---------------- fused QKV fp16 GEMM ----------------
// C[m][n] = sum_k A[m][k]*B[n][k]; A = x (8192x1024), B = one of wq/wk/wv (1024x1024), fp16 in, fp32 out.
// 128x128 tile, BK=64, 4 waves (2x2 of 64x64), 16x16x32 f16 MFMA, single pass.
// LDS 32KB -> ~3 blocks/CU for latency hiding across blocks.
__global__ void __launch_bounds__(256, 3) k_gemm_qkv(
    const _Float16* __restrict__ A,
    const _Float16* __restrict__ wq, const _Float16* __restrict__ wk, const _Float16* __restrict__ wv,
    float* __restrict__ qf, float* __restrict__ kf, float* __restrict__ vf) {
  __shared__ _Float16 lds[16384];            // 32KB: A-tile, B-tile [128][64], 8 16B-units/row, unit^=(row&7)
  _Float16* sA = lds;
  _Float16* sB = lds + 8192;
  const int tid = threadIdx.x;
  const int lane = tid & 63, w = tid >> 6;
  const int wm = w >> 1, wn = w & 1;
  const int l15 = lane & 15, g = lane >> 4;
  const int bid = blockIdx.x;
  const int mt = bid & 63, nt = bid >> 6;    // nt 0..23
  const _Float16* B; float* C;
  if (nt < 8)       { B = wq; C = qf; }
  else if (nt < 16) { B = wk; C = kf; }
  else              { B = wv; C = vf; }
  const int m0 = mt * 128;
  const int n0 = (nt & 7) * 128;

  f32x4 acc[4][4] = {};

  for (int kt = 0; kt < 16; ++kt) {
    const int k0 = kt * 64;
#pragma unroll
    for (int p = 0; p < 4; ++p) {
      int u = p * 256 + tid;
      int row = u >> 3, jp = u & 7;
      int j = jp ^ (row & 7);               // pre-swizzled global source, linear LDS dest
      size_t ga = (size_t)(m0 + row) * 1024 + k0 + j * 8;
      size_t gb = (size_t)(n0 + row) * 1024 + k0 + j * 8;
      gld16(A + ga, sA + u * 8);
      gld16(B + gb, sB + u * 8);
    }
    __syncthreads();
#pragma unroll
    for (int ks = 0; ks < 2; ++ks) {
      h8v fa[4], fb[4];
#pragma unroll
      for (int mf = 0; mf < 4; ++mf) {
        int row = wm * 64 + mf * 16 + l15;
        int off = row * 64 + (((ks * 4 + g) ^ (row & 7)) * 8);
        fa[mf] = *(const h8v*)(sA + off);
      }
#pragma unroll
      for (int nf = 0; nf < 4; ++nf) {
        int row = wn * 64 + nf * 16 + l15;
        int off = row * 64 + (((ks * 4 + g) ^ (row & 7)) * 8);
        fb[nf] = *(const h8v*)(sB + off);
      }
#pragma unroll
      for (int mf = 0; mf < 4; ++mf)
#pragma unroll
        for (int nf = 0; nf < 4; ++nf)
          acc[mf][nf] = mfma16(fa[mf], fb[nf], acc[mf][nf]);
    }
    __syncthreads();
  }
#pragma unroll
  for (int mf = 0; mf < 4; ++mf)
#pragma unroll
    for (int nf = 0; nf < 4; ++nf)
#pragma unroll
      for (int r = 0; r < 4; ++r) {
        int m = m0 + wm * 64 + mf * 16 + g * 4 + r;   // C/D: col=lane&15, row=(lane>>4)*4+r
        int n = n0 + wn * 64 + nf * 16 + l15;
        C[(size_t)m * 1024 + n] = acc[mf][nf][r];
      }
}

// ---------------- RoPE (one tensor) + split -> [B,N,T,H] bf16 hi/lo ----------------
__global__ void __launch_bounds__(256) k_rope(const float* __restrict__ zf,
                                              const float* __restrict__ cs, const float* __restrict__ sn,
                                              u16* __restrict__ zh, u16* __restrict__ zl, float scale) {
  const int bt = blockIdx.x;                 // b*2048 + t
  const int b = bt >> 11, t = bt & 2047;
  __shared__ float sz[1024];
  const int tid = threadIdx.x;
  ((float4*)sz)[tid] = ((const float4*)(zf + (size_t)bt * 1024))[tid];
  __syncthreads();
  const int i0 = tid * 4;
  float4 c4 = ((const float4*)(cs + (size_t)t * 1024))[tid];
  float4 s4 = ((const float4*)(sn + (size_t)t * 1024))[tid];
  float cc[4] = {c4.x, c4.y, c4.z, c4.w};
  float ss[4] = {s4.x, s4.y, s4.z, s4.w};
  u16x4 hv, lv;
#pragma unroll
  for (int j = 0; j < 4; ++j) {
    int i = i0 + j;
    float z;
    if (i < 512) z = sz[i] * cc[j] - sz[2 * i + 1] * ss[j];        // rot[i] = -z[2i+1]
    else         z = sz[i] * cc[j] + sz[2 * (i - 512)] * ss[j];    // rot[512+i'] = z[2i']
    z *= scale;
    u16 h, l;
    split2(z, h, l); hv[j] = h; lv[j] = l;
  }
  const int n = i0 >> 7, hh = i0 & 127;
  const size_t o = ((size_t)(b * 8 + n) * 2048 + t) * 128 + hh;
  *(u16x4*)(zh + o) = hv;
  *(u16x4*)(zl + o) = lv;
}

// ---------------- V transpose + split: [B,T,N*H] fp32 -> [B,N,H,T] bf16 hi/lo ----------------
__global__ void __launch_bounds__(256) k_vtrans(const float* __restrict__ vf,
                                                u16* __restrict__ vth, u16* __restrict__ vtl) {
  const int bid = blockIdx.x;                // (b*8+n)*32 + tt
  const int tt = bid & 31, bn = bid >> 5;
  const int b = bn >> 3, n = bn & 7;
  const int t0 = tt * 64;
  __shared__ float s[64][129];
  const int tid = threadIdx.x;
#pragma unroll
  for (int r8 = 0; r8 < 8; ++r8) {
    int row = r8 * 8 + (tid >> 5);
    int c4 = tid & 31;
    float4 v = *(const float4*)(vf + ((size_t)b * 2048 + t0 + row) * 1024 + n * 128 + c4 * 4);
    s[row][c4 * 4 + 0] = v.x; s[row][c4 * 4 + 1] = v.y;
    s[row][c4 * 4 + 2] = v.z; s[row][c4 * 4 + 3] = v.w;
  }
  __syncthreads();
  const int h = tid >> 1, half = tid & 1;
  const size_t ob = ((size_t)bn * 128 + h) * 2048 + t0 + half * 32;
  u16x8 vh[4], vl[4];
#pragma unroll
  for (int j = 0; j < 32; ++j) {
    u16 a, c;
    split2(s[half * 32 + j][h], a, c);
    vh[j >> 3][j & 7] = a;
    vl[j >> 3][j & 7] = c;
  }
#pragma unroll
  for (int j = 0; j < 4; ++j) {
    *(u16x8*)(vth + ob + j * 8) = vh[j];
    *(u16x8*)(vtl + ob + j * 8) = vl[j];
  }
}

// ---------------- flash attention, split-bf16, swapped operands, QBLK=64 ----------------
// Block: 4 waves, each wave owns 16 q-rows. KVBLK=64. 1024 jobs (32 bn x 32 qt), launched
// big-jobs-first (LPT backfill). St[kk][q] = mfma(K, Q); Ot[h][q] = mfma(Vt, P).
__global__ void __launch_bounds__(256, 2) k_attn(const u16* __restrict__ Qh, const u16* __restrict__ Ql,
                                                 const u16* __restrict__ Kh, const u16* __restrict__ Kl,
                                                 const u16* __restrict__ Vh, const u16* __restrict__ Vl,
                                                 float* __restrict__ Out) {
  const int bid = blockIdx.x;
  const int bn = bid & 31;                   // b*8+n
  const int qt = 31 - (bid >> 5);            // 0..31, descending job size in launch order
  const int b = bn >> 3, n = bn & 7;
  const int q0 = qt * 64;
  const int tid = threadIdx.x;
  const int lane = tid & 63, w = tid >> 6;
  const int l15 = lane & 15, g = lane >> 4;

  __shared__ u16 sm[32768];                  // 64KB
  u16* sKh = sm;                             // [64][128] bf16, 16 16B-units/row, unit^=(row&15)
  u16* sKl = sm + 8192;
  u16* sVh = sm + 16384;                     // [128][64] bf16, 8 units/row, unit^=(row&7)
  u16* sVl = sm + 24576;
  u16* sPh = sKh + w * 1024;                 // P aliases K region after barrier: per-wave [16 q][64 kk]
  u16* sPl = sKl + w * 1024;

  // Q fragments (held in registers for the whole block); q-row = q0 + w*16 + l15
  s8v fqh[4], fql[4];
  {
    const size_t qoff = ((size_t)bn * 2048 + (q0 + w * 16 + l15)) * 128 + g * 8;
#pragma unroll
    for (int hs = 0; hs < 4; ++hs) {
      fqh[hs] = *(const s8v*)(Qh + qoff + hs * 32);
      fql[hs] = *(const s8v*)(Ql + qoff + hs * 32);
    }
  }

  f32x4 ot[8] = {};                          // Ot[h=hf*16+g*4+r][q=l15]
  float mrun = -1e30f;
  float lrun = 0.f;

  const size_t kbase = (size_t)bn * 2048 * 128;   // same flat base for K ([t][h]) and Vt ([h][t])
  const int nkv = qt + 1;

  for (int kv = 0; kv < nkv; ++kv) {
    const int k0 = kv * 64;
    // ---- stage K and Vt tiles (hi+lo), pre-swizzled global source, linear LDS dest
#pragma unroll
    for (int p = 0; p < 4; ++p) {
      int u = p * 256 + tid;
      { int row = u >> 4, jp = u & 15, j = jp ^ (row & 15);
        size_t go = kbase + (size_t)(k0 + row) * 128 + j * 8;
        gld16(Kh + go, sKh + u * 8);
        gld16(Kl + go, sKl + u * 8); }
      { int row = u >> 3, jp = u & 7, j = jp ^ (row & 7);
        size_t go = kbase + (size_t)row * 2048 + k0 + j * 8;
        gld16(Vh + go, sVh + u * 8);
        gld16(Vl + go, sVl + u * 8); }
    }
    __syncthreads();

    // ---- QK^T (swapped): St[kk][q], 3 split passes
    f32x4 st[4] = {};
#pragma unroll
    for (int f = 0; f < 4; ++f) {
      const int row = f * 16 + l15;
      const u16* bh = sKh + row * 128;
      const u16* bl = sKl + row * 128;
#pragma unroll
      for (int hs = 0; hs < 4; ++hs) {
        const int j = (((hs * 4 + g) ^ (row & 15)) * 8);
        s8v akh = *(const s8v*)(bh + j);
        s8v akl = *(const s8v*)(bl + j);
        st[f] = mfma(akh, fqh[hs], st[f]);
        st[f] = mfma(akh, fql[hs], st[f]);
        st[f] = mfma(akl, fqh[hs], st[f]);
      }
    }
    __syncthreads();   // all QK reads of sK done before P overwrites that region

    // ---- mask + online softmax (log2 domain) + P split written to LDS
    {
      const int qg = q0 + w * 16 + l15;
      if (k0 + 63 > q0 + w * 16) {
#pragma unroll
        for (int f = 0; f < 4; ++f)
#pragma unroll
          for (int r = 0; r < 4; ++r)
            if (k0 + f * 16 + g * 4 + r > qg) st[f][r] = -1e30f;
      }
      float tm = -1e30f;
#pragma unroll
      for (int f = 0; f < 4; ++f)
#pragma unroll
        for (int r = 0; r < 4; ++r) tm = fmaxf(tm, st[f][r]);
      tm = fmaxf(tm, __shfl_xor(tm, 16));
      tm = fmaxf(tm, __shfl_xor(tm, 32));
      const float mnew = fmaxf(mrun, tm);
      const float corr = exp2f(mrun - mnew);
      mrun = mnew;
      float ps = 0.f;
      const int q = l15;
#pragma unroll
      for (int f = 0; f < 4; ++f) {
        u16x4 p4h, p4l;
#pragma unroll
        for (int r = 0; r < 4; ++r) {
          float p = exp2f(st[f][r] - mnew);
          ps += p;
          u16 hh, ll;
          split2(p, hh, ll);
          p4h[r] = hh; p4l[r] = ll;
        }
        const int off = q * 64 + (((2 * f + (g >> 1)) ^ (q & 7)) * 8) + (g & 1) * 4;
        *(u16x4*)(sPh + off) = p4h;
        *(u16x4*)(sPl + off) = p4l;
      }
      ps += __shfl_xor(ps, 16);
      ps += __shfl_xor(ps, 32);
      lrun = lrun * corr + ps;
#pragma unroll
      for (int hf = 0; hf < 8; ++hf) {
        ot[hf][0] *= corr; ot[hf][1] *= corr;
        ot[hf][2] *= corr; ot[hf][3] *= corr;
      }
    }
    asm volatile("" ::: "memory");   // keep P ds_writes ordered before PV ds_reads (wave-private, HW in-order)

    // ---- PV: Ot[h][q] += Vt * P (wave-private P, no barrier needed)
    s8v fph[2], fpl[2];
    {
      const int q = l15;
#pragma unroll
      for (int c = 0; c < 2; ++c) {
        const int off = q * 64 + (((4 * c + g) ^ (q & 7)) * 8);
        fph[c] = *(const s8v*)(sPh + off);
        fpl[c] = *(const s8v*)(sPl + off);
      }
    }
#pragma unroll
    for (int hf = 0; hf < 8; ++hf) {
      const int row = hf * 16 + l15;
      const int sw = row & 7;
#pragma unroll
      for (int c = 0; c < 2; ++c) {
        const int off = row * 64 + (((4 * c + g) ^ sw) * 8);
        s8v avh = *(const s8v*)(sVh + off);
        s8v avl = *(const s8v*)(sVl + off);
        ot[hf] = mfma(avh, fph[c], ot[hf]);
        ot[hf] = mfma(avl, fph[c], ot[hf]);
        ot[hf] = mfma(avh, fpl[c], ot[hf]);
      }
    }
    __syncthreads();   // before next tile's staging overwrites sK/sV
  }

  // ---- epilogue: normalize, write out[b, t, n*128+h] as float4 (64B segments)
  {
    const float inv = 1.0f / lrun;
    const int qrow = q0 + w * 16 + l15;
    const size_t ob = ((size_t)b * 2048 + qrow) * 1024 + n * 128;
#pragma unroll
    for (int hf = 0; hf < 8; ++hf) {
      float4 o4;
      o4.x = ot[hf][0] * inv; o4.y = ot[hf][1] * inv;
      o4.z = ot[hf][2] * inv; o4.w = ot[hf][3] * inv;
      *(float4*)(Out + ob + hf * 16 + g * 4) = o4;
    }
  }
}

// ---------------- host ----------------
extern "C" void kernel_launch(void* const* d_in, const int* in_sizes, int n_in,
                              void* d_out, int out_size, void* d_ws, size_t ws_size,
                              hipStream_t stream) {
  const float* x  = (const float*)d_in[0];
  const float* wq = (const float*)d_in[1];
  const float* wk = (const float*)d_in[2];
  const float* wv = (const float*)d_in[3];
  const float* cs = (const float*)d_in[4];
  const float* sn = (const float*)d_in[5];
  float* out = (float*)d_out;

  // Workspace plan (peak 140,509,184 B ~ 134 MiB), lifetime-chained:
  //   xh fp16 [0,16M) ; wq/wk/wv fp16 [16M,22M)      (dead after GEMM)
  //   qf [22M,54M) kf [54M,86M) vf [86M,118M) fp32   (each dead after its rope/vtrans)
  //   qh alias xh [0,16M) ; ql fresh [118M,134M)
  //   kh/kl alias qf ; vth/vtl alias kf
  _Float16* xh  = (_Float16*)d_ws;
  _Float16* wqh = xh + 8388608;
  _Float16* wkh = wqh + 1048576;
  _Float16* wvh = wkh + 1048576;
  float* qf = (float*)(wvh + 1048576);
  float* kf = qf + 8388608;
  float* vf = kf + 8388608;
  u16* qh = (u16*)d_ws;               // aliases xh (dead after GEMM)
  u16* ql = (u16*)(vf + 8388608);     // fresh tail region
  u16* kh = (u16*)qf;                 // aliases qf (dead after rope_q)
  u16* kl = kh + 8388608;
  u16* vth = (u16*)kf;                // aliases kf (dead after rope_k)
  u16* vtl = vth + 8388608;

  if (ws_size < (size_t)140509184) return;  // insufficient scratch -> clean validation failure

  const float QS = 0.08838834764831845f * 1.4426950408889634f;  // 1/sqrt(128) * log2(e)

  k_split_h<<<4096, 256, 0, stream>>>(x, xh, 1048576);
  k_split_h<<<512, 256, 0, stream>>>(wq, wqh, 131072);
  k_split_h<<<512, 256, 0, stream>>>(wk, wkh, 131072);
  k_split_h<<<512, 256, 0, stream>>>(wv, wvh, 131072);
  k_gemm_qkv<<<1536, 256, 0, stream>>>(xh, wqh, wkh, wvh, qf, kf, vf);
  k_rope<<<8192, 256, 0, stream>>>(qf, cs, sn, qh, ql, QS);   // q: fold scale*log2e
  k_rope<<<8192, 256, 0, stream>>>(kf, cs, sn, kh, kl, 1.0f); // k: no scale
  k_vtrans<<<1024, 256, 0, stream>>>(vf, vth, vtl);
  k_attn<<<1024, 256, 0, stream>>>(qh, ql, kh, kl, vth, vtl, out);
}

// Round 6
// 265.023 us; speedup vs baseline: 1.6854x; 1.3831x over previous
//
#include <hip/hip_runtime.h>

typedef unsigned short u16;
typedef unsigned int u32;
typedef _Float16 F16;
typedef __attribute__((ext_vector_type(8))) _Float16 h8v;     // fp16 MFMA fragment (4 VGPR)
typedef __attribute__((ext_vector_type(4))) _Float16 h4v;
typedef __attribute__((ext_vector_type(4))) float f32x4;      // MFMA accumulator

#define DEV __device__ __forceinline__

DEV void gld16(const void* g, void* l) {
  __builtin_amdgcn_global_load_lds((const __attribute__((address_space(1))) void*)g,
                                   (__attribute__((address_space(3))) void*)l, 16, 0, 0);
}
DEV f32x4 mfma16(h8v a, h8v b, f32x4 c) {
  return __builtin_amdgcn_mfma_f32_16x16x32_f16(a, b, c, 0, 0, 0);
}

// ---------------- convert fp32 -> fp16: x then wq|wk|wv in one launch ----------------
__global__ void __launch_bounds__(256) k_split_all(const float* __restrict__ x,
                                                   const float* __restrict__ wq,
                                                   const float* __restrict__ wk,
                                                   const float* __restrict__ wv,
                                                   F16* __restrict__ xh, F16* __restrict__ wh) {
  int i = blockIdx.x * 256 + threadIdx.x;            // group of 8 elems
  const float* src; F16* dst; int li;
  if (i < 1048576)      { src = x;  dst = xh;            li = i; }
  else if (i < 1179648) { src = wq; dst = wh;            li = i - 1048576; }
  else if (i < 1310720) { src = wk; dst = wh + 1048576;  li = i - 1179648; }
  else                  { src = wv; dst = wh + 2097152;  li = i - 1310720; }
  const float4* p = (const float4*)src + (size_t)li * 2;
  float4 a = p[0], b = p[1];
  float v[8] = {a.x, a.y, a.z, a.w, b.x, b.y, b.z, b.w};
  h8v o;
#pragma unroll
  for (int j = 0; j < 8; ++j) o[j] = (F16)v[j];
  ((h8v*)dst)[li] = o;
}

// ---------------- fused QKV fp16 GEMM ----------------
// C[m][n] = sum_k A[m][k]*B[n][k]; A = x (8192x1024), B = wq/wk/wv (1024x1024), fp16 in, fp16 out.
// 128x128 tile, BK=64, 4 waves (2x2 of 64x64), 16x16x32 f16 MFMA.
__global__ void __launch_bounds__(256, 3) k_gemm_qkv(
    const F16* __restrict__ A, const F16* __restrict__ W,
    F16* __restrict__ qf, F16* __restrict__ kf, F16* __restrict__ vf) {
  __shared__ F16 lds[16384];                 // 32KB: A-tile, B-tile [128][64], 8 16B-units/row, unit^=(row&7)
  F16* sA = lds;
  F16* sB = lds + 8192;
  const int tid = threadIdx.x;
  const int lane = tid & 63, w = tid >> 6;
  const int wm = w >> 1, wn = w & 1;
  const int l15 = lane & 15, g = lane >> 4;
  const int bid = blockIdx.x;
  const int mt = bid & 63, nt = bid >> 6;    // nt 0..23
  const F16* B = W + (size_t)(nt >> 3) * 1048576;
  F16* C = (nt < 8) ? qf : (nt < 16) ? kf : vf;
  const int m0 = mt * 128;
  const int n0 = (nt & 7) * 128;

  f32x4 acc[4][4] = {};

  for (int kt = 0; kt < 16; ++kt) {
    const int k0 = kt * 64;
#pragma unroll
    for (int p = 0; p < 4; ++p) {
      int u = p * 256 + tid;
      int row = u >> 3, jp = u & 7;
      int j = jp ^ (row & 7);               // pre-swizzled global source, linear LDS dest
      size_t ga = (size_t)(m0 + row) * 1024 + k0 + j * 8;
      size_t gb = (size_t)(n0 + row) * 1024 + k0 + j * 8;
      gld16(A + ga, sA + u * 8);
      gld16(B + gb, sB + u * 8);
    }
    __syncthreads();
#pragma unroll
    for (int ks = 0; ks < 2; ++ks) {
      h8v fa[4], fb[4];
#pragma unroll
      for (int mf = 0; mf < 4; ++mf) {
        int row = wm * 64 + mf * 16 + l15;
        int off = row * 64 + (((ks * 4 + g) ^ (row & 7)) * 8);
        fa[mf] = *(const h8v*)(sA + off);
      }
#pragma unroll
      for (int nf = 0; nf < 4; ++nf) {
        int row = wn * 64 + nf * 16 + l15;
        int off = row * 64 + (((ks * 4 + g) ^ (row & 7)) * 8);
        fb[nf] = *(const h8v*)(sB + off);
      }
#pragma unroll
      for (int mf = 0; mf < 4; ++mf)
#pragma unroll
        for (int nf = 0; nf < 4; ++nf)
          acc[mf][nf] = mfma16(fa[mf], fb[nf], acc[mf][nf]);
    }
    __syncthreads();
  }
#pragma unroll
  for (int mf = 0; mf < 4; ++mf)
#pragma unroll
    for (int nf = 0; nf < 4; ++nf)
#pragma unroll
      for (int r = 0; r < 4; ++r) {
        int m = m0 + wm * 64 + mf * 16 + g * 4 + r;   // C/D: col=lane&15, row=(lane>>4)*4+r
        int n = n0 + wn * 64 + nf * 16 + l15;
        C[(size_t)m * 1024 + n] = (F16)acc[mf][nf][r];
      }
}

// ---------------- RoPE (one tensor, fp16 in) -> [B,N,T,H] fp16 ----------------
__global__ void __launch_bounds__(256) k_rope(const F16* __restrict__ zf,
                                              const float* __restrict__ cs, const float* __restrict__ sn,
                                              F16* __restrict__ zg, float scale) {
  const int bt = blockIdx.x;                 // b*2048 + t
  const int b = bt >> 11, t = bt & 2047;
  __shared__ float sz[1024];
  const int tid = threadIdx.x;
  {
    h4v zin = ((const h4v*)(zf + (size_t)bt * 1024))[tid];
#pragma unroll
    for (int j = 0; j < 4; ++j) sz[tid * 4 + j] = (float)zin[j];
  }
  __syncthreads();
  const int i0 = tid * 4;
  float4 c4 = ((const float4*)(cs + (size_t)t * 1024))[tid];
  float4 s4 = ((const float4*)(sn + (size_t)t * 1024))[tid];
  float cc[4] = {c4.x, c4.y, c4.z, c4.w};
  float ss[4] = {s4.x, s4.y, s4.z, s4.w};
  h4v ov;
#pragma unroll
  for (int j = 0; j < 4; ++j) {
    int i = i0 + j;
    float z;
    if (i < 512) z = sz[i] * cc[j] - sz[2 * i + 1] * ss[j];        // rot[i] = -z[2i+1]
    else         z = sz[i] * cc[j] + sz[2 * (i - 512)] * ss[j];    // rot[512+i'] = z[2i']
    ov[j] = (F16)(z * scale);
  }
  const int n = i0 >> 7, hh = i0 & 127;
  const size_t o = ((size_t)(b * 8 + n) * 2048 + t) * 128 + hh;
  *(h4v*)(zg + o) = ov;
}

// ---------------- V transpose: [B,T,N*H] fp16 -> [B,N,H,T] fp16 ----------------
__global__ void __launch_bounds__(256) k_vtrans(const F16* __restrict__ vf, F16* __restrict__ vt) {
  const int bid = blockIdx.x;                // (b*8+n)*32 + tt
  const int tt = bid & 31, bn = bid >> 5;
  const int b = bn >> 3, n = bn & 7;
  const int t0 = tt * 64;
  __shared__ float s[64][129];
  const int tid = threadIdx.x;
#pragma unroll
  for (int r8 = 0; r8 < 4; ++r8) {
    int row = r8 * 16 + (tid >> 4);
    int c8 = tid & 15;
    h8v v = *(const h8v*)(vf + ((size_t)b * 2048 + t0 + row) * 1024 + n * 128 + c8 * 8);
#pragma unroll
    for (int k = 0; k < 8; ++k) s[row][c8 * 8 + k] = (float)v[k];
  }
  __syncthreads();
  const int h = tid >> 1, half = tid & 1;
  const size_t ob = ((size_t)bn * 128 + h) * 2048 + t0 + half * 32;
  h8v o[4];
#pragma unroll
  for (int j = 0; j < 32; ++j) o[j >> 3][j & 7] = (F16)s[half * 32 + j][h];
#pragma unroll
  for (int jj = 0; jj < 4; ++jj) *(h8v*)(vt + ob + jj * 8) = o[jj];
}

// ---------------- flash attention, fp16, swapped operands, QBLK=64 ----------------
// 4 waves x 16 q-rows. KVBLK=64. 1024 jobs (32 bn x 32 qt), ALL co-resident at 4 blocks/CU.
// qt remap: CU c hosts ords {o,o+8,o+16,o+24} -> qt {31-o, o, 23-o, o+8}: per-CU sum == 62 steps.
// St[kk][q] = mfma(K, Q); Ot[h][q] = mfma(Vt, P).
__global__ void __launch_bounds__(256, 4) k_attn(const F16* __restrict__ Q, const F16* __restrict__ K,
                                                 const F16* __restrict__ Vt, float* __restrict__ Out) {
  const int bid = blockIdx.x;
  const int bn = bid & 31;                   // b*8+n
  const int o = bid >> 5;                    // [0,32)
  int qt;
  if (o < 8)       qt = 31 - o;
  else if (o < 16) qt = o - 8;
  else if (o < 24) qt = 39 - o;
  else             qt = o - 16;
  const int b = bn >> 3, n = bn & 7;
  const int q0 = qt * 64;
  const int tid = threadIdx.x;
  const int lane = tid & 63, w = tid >> 6;
  const int l15 = lane & 15, g = lane >> 4;

  __shared__ F16 sm[16384];                  // 32KB
  F16* sK = sm;                              // [64][128] fp16, 16 16B-units/row, unit^=(row&15)
  F16* sV = sm + 8192;                       // [128][64] fp16, 8 units/row, unit^=(row&7)
  F16* sP = sK + w * 1024;                   // P aliases K region after barrier: per-wave [16 q][64 kk]

  // Q fragments (held in registers for the whole block); q-row = q0 + w*16 + l15
  h8v fq[4];
  {
    const size_t qoff = ((size_t)bn * 2048 + (q0 + w * 16 + l15)) * 128 + g * 8;
#pragma unroll
    for (int hs = 0; hs < 4; ++hs) fq[hs] = *(const h8v*)(Q + qoff + hs * 32);
  }

  f32x4 ot[8] = {};                          // Ot[h=hf*16+g*4+r][q=l15]
  float mrun = -1e30f;
  float lrun = 0.f;

  const size_t kbase = (size_t)bn * 2048 * 128;   // same flat base for K ([t][h]) and Vt ([h][t])
  const int nkv = qt + 1;

  for (int kv = 0; kv < nkv; ++kv) {
    const int k0 = kv * 64;
    // ---- stage K and Vt tiles, pre-swizzled global source, linear LDS dest
#pragma unroll
    for (int p = 0; p < 4; ++p) {
      int u = p * 256 + tid;
      { int row = u >> 4, jp = u & 15, j = jp ^ (row & 15);
        gld16(K + kbase + (size_t)(k0 + row) * 128 + j * 8, sK + u * 8); }
      { int row = u >> 3, jp = u & 7, j = jp ^ (row & 7);
        gld16(Vt + kbase + (size_t)row * 2048 + k0 + j * 8, sV + u * 8); }
    }
    __syncthreads();

    // ---- QK^T (swapped): St[kk][q]
    f32x4 st[4] = {};
#pragma unroll
    for (int f = 0; f < 4; ++f) {
      const int row = f * 16 + l15;
      const F16* bk = sK + row * 128;
#pragma unroll
      for (int hs = 0; hs < 4; ++hs) {
        const int j = (((hs * 4 + g) ^ (row & 15)) * 8);
        st[f] = mfma16(*(const h8v*)(bk + j), fq[hs], st[f]);
      }
    }
    __syncthreads();   // all QK reads of sK done before P overwrites that region

    // ---- mask + online softmax (log2 domain) + fp16 P written to LDS
    {
      const int qg = q0 + w * 16 + l15;
      if (k0 + 63 > q0 + w * 16) {
#pragma unroll
        for (int f = 0; f < 4; ++f)
#pragma unroll
          for (int r = 0; r < 4; ++r)
            if (k0 + f * 16 + g * 4 + r > qg) st[f][r] = -1e30f;
      }
      float tm = -1e30f;
#pragma unroll
      for (int f = 0; f < 4; ++f)
#pragma unroll
        for (int r = 0; r < 4; ++r) tm = fmaxf(tm, st[f][r]);
      tm = fmaxf(tm, __shfl_xor(tm, 16));
      tm = fmaxf(tm, __shfl_xor(tm, 32));
      const float mnew = fmaxf(mrun, tm);
      const float corr = exp2f(mrun - mnew);
      mrun = mnew;
      float ps = 0.f;
      const int q = l15;
#pragma unroll
      for (int f = 0; f < 4; ++f) {
        h4v p4;
#pragma unroll
        for (int r = 0; r < 4; ++r) {
          float p = exp2f(st[f][r] - mnew);
          ps += p;
          p4[r] = (F16)p;
        }
        const int off = q * 64 + (((2 * f + (g >> 1)) ^ (q & 7)) * 8) + (g & 1) * 4;
        *(h4v*)(sP + off) = p4;
      }
      ps += __shfl_xor(ps, 16);
      ps += __shfl_xor(ps, 32);
      lrun = lrun * corr + ps;
#pragma unroll
      for (int hf = 0; hf < 8; ++hf) {
        ot[hf][0] *= corr; ot[hf][1] *= corr;
        ot[hf][2] *= corr; ot[hf][3] *= corr;
      }
    }
    asm volatile("" ::: "memory");   // keep P ds_writes ordered before PV ds_reads (wave-private, HW in-order)

    // ---- PV: Ot[h][q] += Vt * P (wave-private P, no barrier needed)
    h8v fp[2];
    {
      const int q = l15;
#pragma unroll
      for (int c = 0; c < 2; ++c) {
        const int off = q * 64 + (((4 * c + g) ^ (q & 7)) * 8);
        fp[c] = *(const h8v*)(sP + off);
      }
    }
#pragma unroll
    for (int hf = 0; hf < 8; ++hf) {
      const int row = hf * 16 + l15;
      const int sw = row & 7;
#pragma unroll
      for (int c = 0; c < 2; ++c) {
        const int off = row * 64 + (((4 * c + g) ^ sw) * 8);
        ot[hf] = mfma16(*(const h8v*)(sV + off), fp[c], ot[hf]);
      }
    }
    __syncthreads();   // before next tile's staging overwrites sK/sV
  }

  // ---- epilogue: normalize, write out[b, t, n*128+h] as float4 (64B segments)
  {
    const float inv = 1.0f / lrun;
    const int qrow = q0 + w * 16 + l15;
    const size_t ob = ((size_t)b * 2048 + qrow) * 1024 + n * 128;
#pragma unroll
    for (int hf = 0; hf < 8; ++hf) {
      float4 o4;
      o4.x = ot[hf][0] * inv; o4.y = ot[hf][1] * inv;
      o4.z = ot[hf][2] * inv; o4.w = ot[hf][3] * inv;
      *(float4*)(Out + ob + hf * 16 + g * 4) = o4;
    }
  }
}

// ---------------- host ----------------
extern "C" void kernel_launch(void* const* d_in, const int* in_sizes, int n_in,
                              void* d_out, int out_size, void* d_ws, size_t ws_size,
                              hipStream_t stream) {
  const float* x  = (const float*)d_in[0];
  const float* wq = (const float*)d_in[1];
  const float* wk = (const float*)d_in[2];
  const float* wv = (const float*)d_in[3];
  const float* cs = (const float*)d_in[4];
  const float* sn = (const float*)d_in[5];
  float* out = (float*)d_out;

  // Workspace (all fp16; peak 73,400,320 B), lifetime-chained aliasing:
  //   xh [0,16.7M) ; w [16.7M,23.1M) ; qf/kf/vf 16.7M each -> 73.4M
  //   q^ alias xh (dead after GEMM); k^ alias qf (dead after rope_q); vt alias kf (dead after rope_k)
  F16* xh = (F16*)d_ws;
  F16* wh = xh + 8388608;              // wq,wk,wv contiguous (3 x 1048576)
  F16* qf = wh + 3145728;
  F16* kf = qf + 8388608;
  F16* vf = kf + 8388608;
  F16* qg = xh;                        // aliases
  F16* kg = qf;
  F16* vtg = kf;

  if (ws_size < (size_t)73400320) return;  // insufficient scratch -> clean validation failure

  const float QS = 0.08838834764831845f * 1.4426950408889634f;  // 1/sqrt(128) * log2(e)

  k_split_all<<<5632, 256, 0, stream>>>(x, wq, wk, wv, xh, wh);
  k_gemm_qkv<<<1536, 256, 0, stream>>>(xh, wh, qf, kf, vf);
  k_rope<<<8192, 256, 0, stream>>>(qf, cs, sn, qg, QS);   // q: fold scale*log2e
  k_rope<<<8192, 256, 0, stream>>>(kf, cs, sn, kg, 1.0f); // k: no scale
  k_vtrans<<<1024, 256, 0, stream>>>(vf, vtg);
  k_attn<<<1024, 256, 0, stream>>>(qg, kg, vtg, out);
}

// Round 7
// 257.566 us; speedup vs baseline: 1.7342x; 1.0289x over previous
//
#include <hip/hip_runtime.h>

typedef unsigned short u16;
typedef unsigned int u32;
typedef _Float16 F16;
typedef __attribute__((ext_vector_type(8))) _Float16 h8v;     // fp16 MFMA fragment (4 VGPR)
typedef __attribute__((ext_vector_type(4))) _Float16 h4v;
typedef __attribute__((ext_vector_type(4))) float f32x4;      // MFMA accumulator

#define DEV __device__ __forceinline__

DEV void gld16(const void* g, void* l) {
  __builtin_amdgcn_global_load_lds((const __attribute__((address_space(1))) void*)g,
                                   (__attribute__((address_space(3))) void*)l, 16, 0, 0);
}
DEV f32x4 mfma16(h8v a, h8v b, f32x4 c) {
  return __builtin_amdgcn_mfma_f32_16x16x32_f16(a, b, c, 0, 0, 0);
}

// ---------------- convert fp32 -> fp16: x then wq|wk|wv in one launch ----------------
__global__ void __launch_bounds__(256) k_split_all(const float* __restrict__ x,
                                                   const float* __restrict__ wq,
                                                   const float* __restrict__ wk,
                                                   const float* __restrict__ wv,
                                                   F16* __restrict__ xh, F16* __restrict__ wh) {
  int i = blockIdx.x * 256 + threadIdx.x;            // group of 8 elems
  const float* src; F16* dst; int li;
  if (i < 1048576)      { src = x;  dst = xh;            li = i; }
  else if (i < 1179648) { src = wq; dst = wh;            li = i - 1048576; }
  else if (i < 1310720) { src = wk; dst = wh + 1048576;  li = i - 1179648; }
  else                  { src = wv; dst = wh + 2097152;  li = i - 1310720; }
  const float4* p = (const float4*)src + (size_t)li * 2;
  float4 a = p[0], b = p[1];
  float v[8] = {a.x, a.y, a.z, a.w, b.x, b.y, b.z, b.w};
  h8v o;
#pragma unroll
  for (int j = 0; j < 8; ++j) o[j] = (F16)v[j];
  ((h8v*)dst)[li] = o;
}

// ---------------- fused QKV fp16 GEMM ----------------
// C[m][n] = sum_k A[m][k]*B[n][k]; A = x (8192x1024), B = wq/wk/wv (1024x1024), fp16 in, fp16 out.
// 128x128 tile, BK=64, 4 waves (2x2 of 64x64), 16x16x32 f16 MFMA.
__global__ void __launch_bounds__(256, 3) k_gemm_qkv(
    const F16* __restrict__ A, const F16* __restrict__ W,
    F16* __restrict__ qf, F16* __restrict__ kf, F16* __restrict__ vf) {
  __shared__ F16 lds[16384];                 // 32KB: A-tile, B-tile [128][64], 8 16B-units/row, unit^=(row&7)
  F16* sA = lds;
  F16* sB = lds + 8192;
  const int tid = threadIdx.x;
  const int lane = tid & 63, w = tid >> 6;
  const int wm = w >> 1, wn = w & 1;
  const int l15 = lane & 15, g = lane >> 4;
  const int bid = blockIdx.x;
  const int mt = bid & 63, nt = bid >> 6;    // nt 0..23
  const F16* B = W + (size_t)(nt >> 3) * 1048576;
  F16* C = (nt < 8) ? qf : (nt < 16) ? kf : vf;
  const int m0 = mt * 128;
  const int n0 = (nt & 7) * 128;

  f32x4 acc[4][4] = {};

  for (int kt = 0; kt < 16; ++kt) {
    const int k0 = kt * 64;
#pragma unroll
    for (int p = 0; p < 4; ++p) {
      int u = p * 256 + tid;
      int row = u >> 3, jp = u & 7;
      int j = jp ^ (row & 7);               // pre-swizzled global source, linear LDS dest
      size_t ga = (size_t)(m0 + row) * 1024 + k0 + j * 8;
      size_t gb = (size_t)(n0 + row) * 1024 + k0 + j * 8;
      gld16(A + ga, sA + u * 8);
      gld16(B + gb, sB + u * 8);
    }
    __syncthreads();
#pragma unroll
    for (int ks = 0; ks < 2; ++ks) {
      h8v fa[4], fb[4];
#pragma unroll
      for (int mf = 0; mf < 4; ++mf) {
        int row = wm * 64 + mf * 16 + l15;
        int off = row * 64 + (((ks * 4 + g) ^ (row & 7)) * 8);
        fa[mf] = *(const h8v*)(sA + off);
      }
#pragma unroll
      for (int nf = 0; nf < 4; ++nf) {
        int row = wn * 64 + nf * 16 + l15;
        int off = row * 64 + (((ks * 4 + g) ^ (row & 7)) * 8);
        fb[nf] = *(const h8v*)(sB + off);
      }
#pragma unroll
      for (int mf = 0; mf < 4; ++mf)
#pragma unroll
        for (int nf = 0; nf < 4; ++nf)
          acc[mf][nf] = mfma16(fa[mf], fb[nf], acc[mf][nf]);
    }
    __syncthreads();
  }
#pragma unroll
  for (int mf = 0; mf < 4; ++mf)
#pragma unroll
    for (int nf = 0; nf < 4; ++nf)
#pragma unroll
      for (int r = 0; r < 4; ++r) {
        int m = m0 + wm * 64 + mf * 16 + g * 4 + r;   // C/D: col=lane&15, row=(lane>>4)*4+r
        int n = n0 + wn * 64 + nf * 16 + l15;
        C[(size_t)m * 1024 + n] = (F16)acc[mf][nf][r];
      }
}

// ---------------- fused prep: rope(q&k) + V transpose, one launch ----------------
// blocks [0,8192): rope both q and k for one (b,t) row, sharing one cos/sin read.
// blocks [8192,9216): transpose V [B,T,N*H] -> [B,N,H,T].
__global__ void __launch_bounds__(256) k_prep(const F16* __restrict__ qf, const F16* __restrict__ kf,
                                              const F16* __restrict__ vf,
                                              const float* __restrict__ cs, const float* __restrict__ sn,
                                              F16* __restrict__ qg, F16* __restrict__ kg,
                                              F16* __restrict__ vtg, float QS) {
  __shared__ float smem[8256];               // rope: sq[1024]+sk[1024]; vtrans: [64][129]
  const int bid = blockIdx.x;
  const int tid = threadIdx.x;
  if (bid < 8192) {
    float* sq = smem;
    float* sk = smem + 1024;
    const int b = bid >> 11, t = bid & 2047;
    {
      h4v qi = ((const h4v*)(qf + (size_t)bid * 1024))[tid];
      h4v ki = ((const h4v*)(kf + (size_t)bid * 1024))[tid];
#pragma unroll
      for (int j = 0; j < 4; ++j) { sq[tid * 4 + j] = (float)qi[j]; sk[tid * 4 + j] = (float)ki[j]; }
    }
    __syncthreads();
    const int i0 = tid * 4;
    float4 c4 = ((const float4*)(cs + (size_t)t * 1024))[tid];
    float4 s4 = ((const float4*)(sn + (size_t)t * 1024))[tid];
    float cc[4] = {c4.x, c4.y, c4.z, c4.w};
    float ss[4] = {s4.x, s4.y, s4.z, s4.w};
    h4v qv, kv;
#pragma unroll
    for (int j = 0; j < 4; ++j) {
      int i = i0 + j;
      float zq, zk;
      if (i < 512) { zq = sq[i] * cc[j] - sq[2 * i + 1] * ss[j];          // rot[i] = -z[2i+1]
                     zk = sk[i] * cc[j] - sk[2 * i + 1] * ss[j]; }
      else         { zq = sq[i] * cc[j] + sq[2 * (i - 512)] * ss[j];      // rot[512+i'] = z[2i']
                     zk = sk[i] * cc[j] + sk[2 * (i - 512)] * ss[j]; }
      qv[j] = (F16)(zq * QS);
      kv[j] = (F16)zk;
    }
    const int n = i0 >> 7, hh = i0 & 127;
    const size_t o = ((size_t)(b * 8 + n) * 2048 + t) * 128 + hh;
    *(h4v*)(qg + o) = qv;
    *(h4v*)(kg + o) = kv;
  } else {
    const int vb = bid - 8192;               // (b*8+n)*32 + tt
    const int tt = vb & 31, bn = vb >> 5;
    const int b = bn >> 3, n = bn & 7;
    const int t0 = tt * 64;
    float (*s)[129] = (float(*)[129])smem;
#pragma unroll
    for (int r8 = 0; r8 < 4; ++r8) {
      int row = r8 * 16 + (tid >> 4);
      int c8 = tid & 15;
      h8v v = *(const h8v*)(vf + ((size_t)b * 2048 + t0 + row) * 1024 + n * 128 + c8 * 8);
#pragma unroll
      for (int k = 0; k < 8; ++k) s[row][c8 * 8 + k] = (float)v[k];
    }
    __syncthreads();
    const int h = tid >> 1, half = tid & 1;
    const size_t ob = ((size_t)bn * 128 + h) * 2048 + t0 + half * 32;
    h8v o[4];
#pragma unroll
    for (int j = 0; j < 32; ++j) o[j >> 3][j & 7] = (F16)s[half * 32 + j][h];
#pragma unroll
    for (int jj = 0; jj < 4; ++jj) *(h8v*)(vtg + ob + jj * 8) = o[jj];
  }
}

// ---------------- flash attention, fp16, swapped operands, QBLK=64 ----------------
// 4 waves x 16 q-rows. KVBLK=64. 1024 jobs (32 bn x 32 qt), ALL co-resident at 4 blocks/CU.
// qt remap: CU hosts ords {o,o+8,o+16,o+24} -> per-CU step sum == 62 (balanced).
// P in its own LDS (wave-private): 2 barriers/step. Defer-max skips O-rescale (THR=8, log2).
__global__ void __launch_bounds__(256, 4) k_attn(const F16* __restrict__ Q, const F16* __restrict__ K,
                                                 const F16* __restrict__ Vt, float* __restrict__ Out) {
  const int bid = blockIdx.x;
  const int bn = bid & 31;                   // b*8+n
  const int o = bid >> 5;                    // [0,32)
  int qt;
  if (o < 8)       qt = 31 - o;
  else if (o < 16) qt = o - 8;
  else if (o < 24) qt = 39 - o;
  else             qt = o - 16;
  const int b = bn >> 3, n = bn & 7;
  const int q0 = qt * 64;
  const int tid = threadIdx.x;
  const int lane = tid & 63, w = tid >> 6;
  const int l15 = lane & 15, g = lane >> 4;

  __shared__ F16 sm[20480];                  // 40KB -> 4 blocks/CU
  F16* sK = sm;                              // [64][128] fp16, 16 16B-units/row, unit^=(row&15)
  F16* sV = sm + 8192;                       // [128][64] fp16, 8 units/row, unit^=(row&7)
  F16* sP = sm + 16384 + w * 1024;           // wave-private [16 q][64 kk]

  // Q fragments (held in registers for the whole block); q-row = q0 + w*16 + l15
  h8v fq[4];
  {
    const size_t qoff = ((size_t)bn * 2048 + (q0 + w * 16 + l15)) * 128 + g * 8;
#pragma unroll
    for (int hs = 0; hs < 4; ++hs) fq[hs] = *(const h8v*)(Q + qoff + hs * 32);
  }

  // hoisted staging pointers: 4 phases x {K,V}; bump by constant strides per kv-step
  const size_t kbase = (size_t)bn * 2048 * 128;   // same flat base for K ([t][h]) and Vt ([h][t])
  const F16* kS[4]; const F16* vS[4]; F16* kD[4]; F16* vD[4];
#pragma unroll
  for (int p = 0; p < 4; ++p) {
    int u = p * 256 + tid;
    { int row = u >> 4, jp = u & 15, j = jp ^ (row & 15);
      kS[p] = K + kbase + (size_t)row * 128 + j * 8;
      kD[p] = sK + u * 8; }
    { int row = u >> 3, jp = u & 7, j = jp ^ (row & 7);
      vS[p] = Vt + kbase + (size_t)row * 2048 + j * 8;
      vD[p] = sV + u * 8; }
  }

  f32x4 ot[8] = {};                          // Ot[h=hf*16+g*4+r][q=l15]
  float mrun = -1e30f;
  float lrun = 0.f;
  const int nkv = qt + 1;

  for (int kv = 0; kv < nkv; ++kv) {
    const int k0 = kv * 64;
    // ---- stage K and Vt tiles (pre-swizzled source, linear LDS dest)
#pragma unroll
    for (int p = 0; p < 4; ++p) {
      gld16(kS[p], kD[p]);
      gld16(vS[p], vD[p]);
      kS[p] += 8192;                         // 64 rows x 128
      vS[p] += 64;                           // 64 cols
    }
    __syncthreads();

    // ---- QK^T (swapped): St[kk][q]
    f32x4 st[4] = {};
#pragma unroll
    for (int f = 0; f < 4; ++f) {
      const int row = f * 16 + l15;
      const F16* bk = sK + row * 128;
#pragma unroll
      for (int hs = 0; hs < 4; ++hs) {
        const int j = (((hs * 4 + g) ^ (row & 15)) * 8);
        st[f] = mfma16(*(const h8v*)(bk + j), fq[hs], st[f]);
      }
    }

    // ---- mask + online softmax (log2 domain, defer-max) + fp16 P to wave-private LDS
    {
      const int qg = q0 + w * 16 + l15;
      if (k0 + 63 > q0 + w * 16) {
#pragma unroll
        for (int f = 0; f < 4; ++f)
#pragma unroll
          for (int r = 0; r < 4; ++r)
            if (k0 + f * 16 + g * 4 + r > qg) st[f][r] = -1e30f;
      }
      float tm = -1e30f;
#pragma unroll
      for (int f = 0; f < 4; ++f)
#pragma unroll
        for (int r = 0; r < 4; ++r) tm = fmaxf(tm, st[f][r]);
      tm = fmaxf(tm, __shfl_xor(tm, 16));
      tm = fmaxf(tm, __shfl_xor(tm, 32));
      float corr = 1.f;
      const bool resc = !__all(tm <= mrun + 8.0f);   // wave-uniform
      if (resc) {
        const float mn = fmaxf(mrun, tm);
        corr = exp2f(mrun - mn);
        mrun = mn;
      }
      float ps = 0.f;
      const int q = l15;
#pragma unroll
      for (int f = 0; f < 4; ++f) {
        h4v p4;
#pragma unroll
        for (int r = 0; r < 4; ++r) {
          float p = exp2f(st[f][r] - mrun);
          ps += p;
          p4[r] = (F16)p;
        }
        const int off = q * 64 + (((2 * f + (g >> 1)) ^ (q & 7)) * 8) + (g & 1) * 4;
        *(h4v*)(sP + off) = p4;
      }
      ps += __shfl_xor(ps, 16);
      ps += __shfl_xor(ps, 32);
      lrun = lrun * corr + ps;
      if (resc) {
#pragma unroll
        for (int hf = 0; hf < 8; ++hf) {
          ot[hf][0] *= corr; ot[hf][1] *= corr;
          ot[hf][2] *= corr; ot[hf][3] *= corr;
        }
      }
    }
    asm volatile("" ::: "memory");   // keep P ds_writes ordered before PV ds_reads (wave-private, HW in-order)

    // ---- PV: Ot[h][q] += Vt * P (wave-private P, no barrier needed)
    h8v fp[2];
    {
      const int q = l15;
#pragma unroll
      for (int c = 0; c < 2; ++c) {
        const int off = q * 64 + (((4 * c + g) ^ (q & 7)) * 8);
        fp[c] = *(const h8v*)(sP + off);
      }
    }
#pragma unroll
    for (int hf = 0; hf < 8; ++hf) {
      const int row = hf * 16 + l15;
      const int sw = row & 7;
#pragma unroll
      for (int c = 0; c < 2; ++c) {
        const int off = row * 64 + (((4 * c + g) ^ sw) * 8);
        ot[hf] = mfma16(*(const h8v*)(sV + off), fp[c], ot[hf]);
      }
    }
    __syncthreads();   // before next tile's staging overwrites sK/sV
  }

  // ---- epilogue: normalize, write out[b, t, n*128+h] as float4 (64B segments)
  {
    const float inv = 1.0f / lrun;
    const int qrow = q0 + w * 16 + l15;
    const size_t ob = ((size_t)b * 2048 + qrow) * 1024 + n * 128;
#pragma unroll
    for (int hf = 0; hf < 8; ++hf) {
      float4 o4;
      o4.x = ot[hf][0] * inv; o4.y = ot[hf][1] * inv;
      o4.z = ot[hf][2] * inv; o4.w = ot[hf][3] * inv;
      *(float4*)(Out + ob + hf * 16 + g * 4) = o4;
    }
  }
}

// ---------------- host ----------------
extern "C" void kernel_launch(void* const* d_in, const int* in_sizes, int n_in,
                              void* d_out, int out_size, void* d_ws, size_t ws_size,
                              hipStream_t stream) {
  const float* x  = (const float*)d_in[0];
  const float* wq = (const float*)d_in[1];
  const float* wk = (const float*)d_in[2];
  const float* wv = (const float*)d_in[3];
  const float* cs = (const float*)d_in[4];
  const float* sn = (const float*)d_in[5];
  float* out = (float*)d_out;

  // Workspace (fp16; peak 106,954,752 B). qg aliases xh (dead after GEMM);
  // kg/vtg get fresh regions (fused prep reads qf/kf/vf concurrently — no overlap allowed).
  F16* xh  = (F16*)d_ws;               // 16,777,216 B
  F16* wh  = xh + 8388608;             //  6,291,456 B (wq,wk,wv contiguous)
  F16* qf  = wh + 3145728;             // 16,777,216 B
  F16* kf  = qf + 8388608;             // 16,777,216 B
  F16* vf  = kf + 8388608;             // 16,777,216 B
  F16* kg  = vf + 8388608;             // 16,777,216 B
  F16* vtg = kg + 8388608;             // 16,777,216 B
  F16* qg  = xh;                       // alias

  if (ws_size < (size_t)106954752) return;  // insufficient scratch -> clean validation failure

  const float QS = 0.08838834764831845f * 1.4426950408889634f;  // 1/sqrt(128) * log2(e)

  k_split_all<<<5632, 256, 0, stream>>>(x, wq, wk, wv, xh, wh);
  k_gemm_qkv<<<1536, 256, 0, stream>>>(xh, wh, qf, kf, vf);
  k_prep<<<9216, 256, 0, stream>>>(qf, kf, vf, cs, sn, qg, kg, vtg, QS);
  k_attn<<<1024, 256, 0, stream>>>(qg, kg, vtg, out);
}